// Round 18
// baseline (154.421 us; speedup 1.0000x reference)
//
#include <hip/hip_runtime.h>
#include <hip/hip_bf16.h>
#include <stdint.h>

// B=4, M=256, N=64, D=512, C=1024
// out[b,m,n,c] = log_softmax_c( tanh(pe[b,m,:] + pd[b,n,:]) . W2[c,:] + b2[c] )
// pe = enc @ W1[:, :D]^T ; pd = dec @ W1[:, D:]^T + b1
// log_softmax WITHOUT the max pass (logits bounded ~18 -> f32-safe).
// GEMM: v_mfma_f32_32x32x16_bf16; B staged via global_load_lds into per-wave
// double-buffered LDS panels (no barriers in the k-loop; counted vmcnt(2)).
// CORRECTNESS FENCE (R15/R17 lesson): the k-loop TOP sched_barrier(0) is
// load-bearing — without it the scheduler hoists stage16(i+2) (which writes
// LDS buffer (i+2)&1 == i&1) above iteration i's ds_reads of that same
// buffer -> intermittent corruption. Do not remove.
// W2t layout (both sides): idx = w*32768 + ks*1024 + cb*512 + l*8 + e
//   col = w*64 + cb*32 + (l&31),  k = ks*16 + (l>>5)*8 + e

typedef __bf16         bf16x8 __attribute__((ext_vector_type(8)));
typedef float          f32x4  __attribute__((ext_vector_type(4)));
typedef float          f32x16 __attribute__((ext_vector_type(16)));
typedef unsigned short u16x8  __attribute__((ext_vector_type(8)));

__device__ __forceinline__ unsigned short f2bf(float f) {
  unsigned int u = __float_as_uint(f);
  u += 0x7fffu + ((u >> 16) & 1u);          // RNE
  return (unsigned short)(u >> 16);
}

__device__ __forceinline__ u16x8 cvt8(const float* p) {
  const float4 a = *(const float4*)p;
  const float4 b = *(const float4*)(p + 4);
  u16x8 r;
  r[0] = f2bf(a.x); r[1] = f2bf(a.y); r[2] = f2bf(a.z); r[3] = f2bf(a.w);
  r[4] = f2bf(b.x); r[5] = f2bf(b.y); r[6] = f2bf(b.z); r[7] = f2bf(b.w);
  return r;
}

__device__ __forceinline__ f32x4 mfma16(u16x8 a, u16x8 b, f32x4 c) {
  return __builtin_amdgcn_mfma_f32_16x16x32_bf16(
      __builtin_bit_cast(bf16x8, a), __builtin_bit_cast(bf16x8, b), c, 0, 0, 0);
}
__device__ __forceinline__ f32x16 mfma32(u16x8 a, u16x8 b, f32x16 c) {
  return __builtin_amdgcn_mfma_f32_32x32x16_bf16(
      __builtin_bit_cast(bf16x8, a), __builtin_bit_cast(bf16x8, b), c, 0, 0, 0);
}

// async global->LDS, 16B/lane: lane i's 16B lands at ldsbase + i*16.
__device__ __forceinline__ void stage16(const void* g, void* l) {
  __builtin_amdgcn_global_load_lds(
      (const __attribute__((address_space(1))) void*)g,
      (__attribute__((address_space(3))) void*)l, 16, 0, 0);
}

// ---------------- prep_proj (fused): proj from f32 inputs + W2 tiling -------
// grid = 288 blocks x 256 threads.
//   blocks   0..127: pe tile (rtile = bid>>3 in 0..15, ctile = bid&7)
//   blocks 128..159: pd tile (+ b1)
//   blocks 160..287: W2 -> W2t bf16 tiling (4096 els/block)
__global__ __launch_bounds__(256) void prep_proj_kernel(
    const float* __restrict__ enc, const float* __restrict__ dec,
    const float* __restrict__ W1,  const float* __restrict__ W2,
    const float* __restrict__ b1,
    unsigned short* __restrict__ W2t, float* __restrict__ pe, float* __restrict__ pd)
{
  const int bid = blockIdx.x;
  if (bid >= 160) {
    const int base = (bid - 160) * 4096;
#pragma unroll
    for (int j = 0; j < 16; ++j) {
      const int i = base + j * 256 + threadIdx.x;
      // decode idx = w*32768 + ks*1024 + cb*512 + l*8 + e
      const int e  = i & 7;
      const int l  = (i >> 3) & 63;
      const int cb = (i >> 9) & 1;
      const int ks = (i >> 10) & 31;
      const int w  = i >> 15;                      // 0..15
      const int col = w * 64 + cb * 32 + (l & 31);
      const int k   = ks * 16 + (l >> 5) * 8 + e;
      W2t[i] = f2bf(W2[col * 512 + k]);
    }
    return;
  }

  int pb = bid;
  const float* Af;
  const float* bias;
  float* outp;
  int woff;
  if (pb < 128) { Af = enc; bias = nullptr; outp = pe; woff = 0; }
  else { pb -= 128; Af = dec; bias = b1; outp = pd; woff = 512; }
  const int rtile = pb >> 3;
  const int ctile = pb & 7;
  const int w = threadIdx.x >> 6;
  const int l = threadIdx.x & 63;
  const int q = l >> 4, ln = l & 15;

  f32x4 acc[4] = {};
  const float* Ab = Af + (size_t)(rtile * 64 + ln) * 512 + q * 8;
  const float* Wb = W1 + (size_t)(ctile * 64 + w * 16 + ln) * 1024 + woff + q * 8;

  for (int ks = 0; ks < 16; ++ks) {
    u16x8 bv = cvt8(Wb + ks * 32);
#pragma unroll
    for (int rf = 0; rf < 4; ++rf) {
      u16x8 av = cvt8(Ab + rf * 16 * 512 + ks * 32);
      acc[rf] = mfma16(av, bv, acc[rf]);
    }
  }
  const int col = ctile * 64 + w * 16 + ln;
  const float bv = bias ? bias[col] : 0.0f;
#pragma unroll
  for (int rf = 0; rf < 4; ++rf)
#pragma unroll
    for (int j = 0; j < 4; ++j)
      outp[(size_t)(rtile * 64 + rf * 16 + q * 4 + j) * 512 + col] = acc[rf][j] + bv;
}

// ---------------- joint: fused tanh-GEMM(32x32, LDS-staged B) + log_softmax --
// grid = B*M = 1024 blocks, block = 1024 threads (16 waves).
// Wave w: all 64 rows x cols [w*64, w*64+64) via 2x2 fragments of 32x32.
__global__ __launch_bounds__(1024) void joint_kernel(
    const float* __restrict__ pe, const float* __restrict__ pd,
    const unsigned short* __restrict__ W2t, const float* __restrict__ b2,
    float* __restrict__ out)
{
  __shared__ unsigned short A_sh[64 * 512];    // 64 KiB, XOR-swizzled bf16 tile
  __shared__ unsigned short B_sh[16 * 2048];   // 64 KiB: per-wave 2-buf x 1024 els
  __shared__ float red[64][17];                // per-row, per-wave sum2exp (padded)
  __shared__ float lse_sh[64];

  const int blk = blockIdx.x;            // b*256 + m
  const int b   = blk >> 8;
  const int tid = threadIdx.x;
  const int w = tid >> 6, l = tid & 63;
  const int lo = l & 31, hi = l >> 5;

  const unsigned short* Wsrc = W2t + (size_t)w * 32768;   // this wave's panel
  unsigned short* Bdst = B_sh + w * 2048;                 // wave-uniform base

  // stage chunk 0 (buf 0) — L2 latency hides under the gen phase
  stage16(Wsrc + l * 8,       Bdst);
  stage16(Wsrc + 512 + l * 8, Bdst + 512);

  // b2: load AND pin consumption before the barrier (keep-alive) so no
  // non-stage vmem op can be sunk into the k-loop (vmcnt count depends on it)
  float b2v[2];
#pragma unroll
  for (int cb = 0; cb < 2; ++cb) b2v[cb] = b2[w * 64 + cb * 32 + lo];
  asm volatile("" :: "v"(b2v[0]), "v"(b2v[1]));

  // ---- generate A[n][d] = tanh(pe[m,d] + pd[n,d]) into swizzled LDS ----
  // wave w owns rows w*4..w*4+3; lane l owns d = l*8..l*8+7 (coalesced).
  {
    const float* per = pe + (size_t)blk * 512 + l * 8;
    const float4 pe0 = *(const float4*)(per);
    const float4 pe1 = *(const float4*)(per + 4);
#pragma unroll
    for (int r = 0; r < 4; ++r) {
      const int n = (w << 2) | r;
      const float* pdr = pd + (size_t)((b << 6) | n) * 512 + l * 8;
      const float4 q0 = *(const float4*)(pdr);
      const float4 q1 = *(const float4*)(pdr + 4);
      float x[8] = {pe0.x + q0.x, pe0.y + q0.y, pe0.z + q0.z, pe0.w + q0.w,
                    pe1.x + q1.x, pe1.y + q1.y, pe1.z + q1.z, pe1.w + q1.w};
      u16x8 pk;
#pragma unroll
      for (int e = 0; e < 8; ++e) {
        const float ex = __expf(2.0f * x[e]);                    // tanh = 1 - 2/(e^2x+1)
        const float tv = 1.0f - 2.0f * __builtin_amdgcn_rcpf(ex + 1.0f);
        pk[e] = f2bf(tv);
      }
      *(u16x8*)((char*)A_sh + n * 1024 + ((l ^ (n & 7)) << 4)) = pk;
    }
  }
  __syncthreads();   // A ready; drains gen loads + b2 + stage(0): vmcnt = 0 here

  // ---- GEMM: barrier-free k-loop; per-wave private B double-buffer ----
  f32x16 acc[2][2];
#pragma unroll
  for (int rb = 0; rb < 2; ++rb)
#pragma unroll
    for (int cb = 0; cb < 2; ++cb) acc[rb][cb] = (f32x16)(0.f);

  const char* Abase = (const char*)A_sh + lo * 1024;   // + rb*32768
  const int x7 = lo & 7;
  const unsigned short* Bread = B_sh + w * 2048 + l * 8;

#pragma unroll
  for (int ks = 0; ks < 32; ++ks) {
    // LOAD-BEARING fence: blocks stage16(ks+1) (same-buffer write as the
    // PREVIOUS iteration's bv reads when hoisted) from moving up. See header.
    __builtin_amdgcn_sched_barrier(0);
    if (ks < 31) {
      // stage next chunk into the other buffer (private region, no race)
      stage16(Wsrc + (ks + 1) * 1024 + l * 8,       Bdst + ((ks + 1) & 1) * 1024);
      stage16(Wsrc + (ks + 1) * 1024 + 512 + l * 8, Bdst + ((ks + 1) & 1) * 1024 + 512);
      __builtin_amdgcn_sched_barrier(0);
      asm volatile("s_waitcnt vmcnt(2)" ::: "memory");   // chunk ks landed
    } else {
      asm volatile("s_waitcnt vmcnt(0)" ::: "memory");
    }
    __builtin_amdgcn_sched_barrier(0);

    u16x8 bv[2], av[2];
#pragma unroll
    for (int cb = 0; cb < 2; ++cb)
      bv[cb] = *(const u16x8*)(Bread + (ks & 1) * 1024 + cb * 512);
#pragma unroll
    for (int rb = 0; rb < 2; ++rb)
      av[rb] = *(const u16x8*)(Abase + rb * 32768 + (((2 * ks + hi) ^ x7) << 4));
#pragma unroll
    for (int rb = 0; rb < 2; ++rb)
#pragma unroll
      for (int cb = 0; cb < 2; ++cb)
        acc[rb][cb] = mfma32(av[rb], bv[cb], acc[rb][cb]);
  }

  // ---- epilogue: + b2, row-sums of 2^(x*log2e), per-rb to limit live regs ----
  // thread holds: cols {w*64 + cb*32 + lo}, rows {rb*32 + (reg&3)+8*(reg>>2)+4*hi}.
  const float L2E = 1.4426950408889634f;
  const float LN2 = 0.6931471805599453f;

#pragma unroll
  for (int rb = 0; rb < 2; ++rb) {
    float s[16];
#pragma unroll
    for (int reg = 0; reg < 16; ++reg) {
      const float x0 = acc[rb][0][reg] + b2v[0];
      const float x1 = acc[rb][1][reg] + b2v[1];
      acc[rb][0][reg] = x0;
      acc[rb][1][reg] = x1;
      s[reg] = __builtin_amdgcn_exp2f(x0 * L2E) + __builtin_amdgcn_exp2f(x1 * L2E);
    }
#pragma unroll
    for (int o = 1; o < 32; o <<= 1)
#pragma unroll
      for (int reg = 0; reg < 16; ++reg)
        s[reg] += __shfl_xor(s[reg], o);
    if (lo == 0) {
#pragma unroll
      for (int reg = 0; reg < 16; ++reg) {
        const int row = rb * 32 + (reg & 3) + 8 * (reg >> 2) + 4 * hi;
        red[row][w] = s[reg];
      }
    }
  }
  __syncthreads();

  // merge the 16 wave-partials: thread tid<64 handles row tid
  if (tid < 64) {
    float s = red[tid][0];
#pragma unroll
    for (int ww = 1; ww < 16; ++ww) s += red[tid][ww];
    lse_sh[tid] = LN2 * __builtin_amdgcn_logf(s);   // v_log_f32 = log2
  }
  __syncthreads();

  // final: out = acc - lse
  float* outb = out + (size_t)blk * 65536 + w * 64 + lo;
#pragma unroll
  for (int rb = 0; rb < 2; ++rb)
#pragma unroll
    for (int reg = 0; reg < 16; ++reg) {
      const int row = rb * 32 + (reg & 3) + 8 * (reg >> 2) + 4 * hi;
      const float lse = lse_sh[row];
      float* orow = outb + (size_t)row * 1024;
      orow[0]  = acc[rb][0][reg] - lse;
      orow[32] = acc[rb][1][reg] - lse;
    }
}

extern "C" void kernel_launch(void* const* d_in, const int* in_sizes, int n_in,
                              void* d_out, int out_size, void* d_ws, size_t ws_size,
                              hipStream_t stream) {
  (void)in_sizes; (void)n_in; (void)out_size; (void)ws_size;
  const float* enc = (const float*)d_in[0];
  const float* dec = (const float*)d_in[1];
  const float* W1  = (const float*)d_in[2];
  const float* b1  = (const float*)d_in[3];
  const float* W2  = (const float*)d_in[4];
  const float* b2  = (const float*)d_in[5];
  float* out = (float*)d_out;

  char* ws = (char*)d_ws;
  unsigned short* W2t = (unsigned short*)(ws + 0);         // 1 MiB (524288 el, tiled)
  float*          pe  = (float*)(ws + 1048576);            // 2 MiB  [1024][512]
  float*          pd  = (float*)(ws + 3145728);            // 512 KiB [256][512]

  prep_proj_kernel<<<288, 256, 0, stream>>>(enc, dec, W1, W2, b1, W2t, pe, pd);
  joint_kernel<<<1024, 1024, 0, stream>>>(pe, pd, W2t, b2, out);
}

// Round 19
// 141.057 us; speedup vs baseline: 1.0947x; 1.0947x over previous
//
#include <hip/hip_runtime.h>
#include <hip/hip_bf16.h>
#include <stdint.h>

// B=4, M=256, N=64, D=512, C=1024
// out[b,m,n,c] = log_softmax_c( tanh(pe[b,m,:] + pd[b,n,:]) . W2[c,:] + b2[c] )
// pe = enc @ W1[:, :D]^T ; pd = dec @ W1[:, D:]^T + b1
// log_softmax WITHOUT the max pass (logits bounded ~18 -> f32-safe).
// GEMM: v_mfma_f32_32x32x16_bf16; B staged via global_load_lds into per-wave
// double-buffered LDS panels (no barriers in the k-loop; counted vmcnt(2)).
// CORRECTNESS FENCE (R15/R17 lesson): the k-loop TOP sched_barrier(0) is
// load-bearing — without it the scheduler hoists stage16(i+2) (which writes
// LDS buffer (i+2)&1 == i&1) above iteration i's ds_reads of that same
// buffer -> intermittent corruption. Do not remove.
// R19: epilogue row-sum uses fold-reduce (62 shuffles vs 160); prep W2-tiling
// reads coalesced (thread->(col,k8)), writes scattered 16B.
// W2t layout (both sides): idx = w*32768 + ks*1024 + cb*512 + l*8 + e
//   col = w*64 + cb*32 + (l&31),  k = ks*16 + (l>>5)*8 + e

typedef __bf16         bf16x8 __attribute__((ext_vector_type(8)));
typedef float          f32x4  __attribute__((ext_vector_type(4)));
typedef float          f32x16 __attribute__((ext_vector_type(16)));
typedef unsigned short u16x8  __attribute__((ext_vector_type(8)));

__device__ __forceinline__ unsigned short f2bf(float f) {
  unsigned int u = __float_as_uint(f);
  u += 0x7fffu + ((u >> 16) & 1u);          // RNE
  return (unsigned short)(u >> 16);
}

__device__ __forceinline__ u16x8 cvt8(const float* p) {
  const float4 a = *(const float4*)p;
  const float4 b = *(const float4*)(p + 4);
  u16x8 r;
  r[0] = f2bf(a.x); r[1] = f2bf(a.y); r[2] = f2bf(a.z); r[3] = f2bf(a.w);
  r[4] = f2bf(b.x); r[5] = f2bf(b.y); r[6] = f2bf(b.z); r[7] = f2bf(b.w);
  return r;
}

__device__ __forceinline__ f32x4 mfma16(u16x8 a, u16x8 b, f32x4 c) {
  return __builtin_amdgcn_mfma_f32_16x16x32_bf16(
      __builtin_bit_cast(bf16x8, a), __builtin_bit_cast(bf16x8, b), c, 0, 0, 0);
}
__device__ __forceinline__ f32x16 mfma32(u16x8 a, u16x8 b, f32x16 c) {
  return __builtin_amdgcn_mfma_f32_32x32x16_bf16(
      __builtin_bit_cast(bf16x8, a), __builtin_bit_cast(bf16x8, b), c, 0, 0, 0);
}

// async global->LDS, 16B/lane: lane i's 16B lands at ldsbase + i*16.
__device__ __forceinline__ void stage16(const void* g, void* l) {
  __builtin_amdgcn_global_load_lds(
      (const __attribute__((address_space(1))) void*)g,
      (__attribute__((address_space(3))) void*)l, 16, 0, 0);
}

// ---------------- prep_proj (fused): proj from f32 inputs + W2 tiling -------
// grid = 288 blocks x 256 threads.
//   blocks   0..127: pe tile (rtile = bid>>3 in 0..15, ctile = bid&7)
//   blocks 128..159: pd tile (+ b1)
//   blocks 160..287: W2 -> W2t bf16 tiling, COALESCED reads
__global__ __launch_bounds__(256) void prep_proj_kernel(
    const float* __restrict__ enc, const float* __restrict__ dec,
    const float* __restrict__ W1,  const float* __restrict__ W2,
    const float* __restrict__ b1,
    unsigned short* __restrict__ W2t, float* __restrict__ pe, float* __restrict__ pd)
{
  const int bid = blockIdx.x;
  if (bid >= 160) {
    // thread -> (col, k8): reads contiguous (2KB per 64-tid group), writes 16B scattered
#pragma unroll
    for (int j = 0; j < 2; ++j) {
      const int idx = (bid - 160) * 512 + j * 256 + threadIdx.x;   // 0..65535
      const int k8  = idx & 63;
      const int col = idx >> 6;
      const u16x8 v = cvt8(W2 + (size_t)col * 512 + k8 * 8);
      const int w  = col >> 6, cb = (col >> 5) & 1;
      const int ks = k8 >> 1;
      const int l  = (col & 31) | ((k8 & 1) << 5);
      *(u16x8*)(W2t + ((size_t)w * 32768 + ks * 1024 + cb * 512 + l * 8)) = v;
    }
    return;
  }

  int pb = bid;
  const float* Af;
  const float* bias;
  float* outp;
  int woff;
  if (pb < 128) { Af = enc; bias = nullptr; outp = pe; woff = 0; }
  else { pb -= 128; Af = dec; bias = b1; outp = pd; woff = 512; }
  const int rtile = pb >> 3;
  const int ctile = pb & 7;
  const int w = threadIdx.x >> 6;
  const int l = threadIdx.x & 63;
  const int q = l >> 4, ln = l & 15;

  f32x4 acc[4] = {};
  const float* Ab = Af + (size_t)(rtile * 64 + ln) * 512 + q * 8;
  const float* Wb = W1 + (size_t)(ctile * 64 + w * 16 + ln) * 1024 + woff + q * 8;

  for (int ks = 0; ks < 16; ++ks) {
    u16x8 bv = cvt8(Wb + ks * 32);
#pragma unroll
    for (int rf = 0; rf < 4; ++rf) {
      u16x8 av = cvt8(Ab + rf * 16 * 512 + ks * 32);
      acc[rf] = mfma16(av, bv, acc[rf]);
    }
  }
  const int col = ctile * 64 + w * 16 + ln;
  const float bv = bias ? bias[col] : 0.0f;
#pragma unroll
  for (int rf = 0; rf < 4; ++rf)
#pragma unroll
    for (int j = 0; j < 4; ++j)
      outp[(size_t)(rtile * 64 + rf * 16 + q * 4 + j) * 512 + col] = acc[rf][j] + bv;
}

// ---------------- joint: fused tanh-GEMM(32x32, LDS-staged B) + log_softmax --
// grid = B*M = 1024 blocks, block = 1024 threads (16 waves).
// Wave w: all 64 rows x cols [w*64, w*64+64) via 2x2 fragments of 32x32.
__global__ __launch_bounds__(1024) void joint_kernel(
    const float* __restrict__ pe, const float* __restrict__ pd,
    const unsigned short* __restrict__ W2t, const float* __restrict__ b2,
    float* __restrict__ out)
{
  __shared__ unsigned short A_sh[64 * 512];    // 64 KiB, XOR-swizzled bf16 tile
  __shared__ unsigned short B_sh[16 * 2048];   // 64 KiB: per-wave 2-buf x 1024 els
  __shared__ float red[64][17];                // per-row, per-wave sum2exp (padded)
  __shared__ float lse_sh[64];

  const int blk = blockIdx.x;            // b*256 + m
  const int b   = blk >> 8;
  const int tid = threadIdx.x;
  const int w = tid >> 6, l = tid & 63;
  const int lo = l & 31, hi = l >> 5;

  const unsigned short* Wsrc = W2t + (size_t)w * 32768;   // this wave's panel
  unsigned short* Bdst = B_sh + w * 2048;                 // wave-uniform base

  // stage chunk 0 (buf 0) — L2 latency hides under the gen phase
  stage16(Wsrc + l * 8,       Bdst);
  stage16(Wsrc + 512 + l * 8, Bdst + 512);

  // b2: load AND pin consumption before the barrier (keep-alive) so no
  // non-stage vmem op can be sunk into the k-loop (vmcnt count depends on it)
  float b2v[2];
#pragma unroll
  for (int cb = 0; cb < 2; ++cb) b2v[cb] = b2[w * 64 + cb * 32 + lo];
  asm volatile("" :: "v"(b2v[0]), "v"(b2v[1]));

  // ---- generate A[n][d] = tanh(pe[m,d] + pd[n,d]) into swizzled LDS ----
  // wave w owns rows w*4..w*4+3; lane l owns d = l*8..l*8+7 (coalesced).
  {
    const float* per = pe + (size_t)blk * 512 + l * 8;
    const float4 pe0 = *(const float4*)(per);
    const float4 pe1 = *(const float4*)(per + 4);
#pragma unroll
    for (int r = 0; r < 4; ++r) {
      const int n = (w << 2) | r;
      const float* pdr = pd + (size_t)((b << 6) | n) * 512 + l * 8;
      const float4 q0 = *(const float4*)(pdr);
      const float4 q1 = *(const float4*)(pdr + 4);
      float x[8] = {pe0.x + q0.x, pe0.y + q0.y, pe0.z + q0.z, pe0.w + q0.w,
                    pe1.x + q1.x, pe1.y + q1.y, pe1.z + q1.z, pe1.w + q1.w};
      u16x8 pk;
#pragma unroll
      for (int e = 0; e < 8; ++e) {
        const float ex = __expf(2.0f * x[e]);                    // tanh = 1 - 2/(e^2x+1)
        const float tv = 1.0f - 2.0f * __builtin_amdgcn_rcpf(ex + 1.0f);
        pk[e] = f2bf(tv);
      }
      *(u16x8*)((char*)A_sh + n * 1024 + ((l ^ (n & 7)) << 4)) = pk;
    }
  }
  __syncthreads();   // A ready; drains gen loads + b2 + stage(0): vmcnt = 0 here

  // ---- GEMM: barrier-free k-loop; per-wave private B double-buffer ----
  f32x16 acc[2][2];
#pragma unroll
  for (int rb = 0; rb < 2; ++rb)
#pragma unroll
    for (int cb = 0; cb < 2; ++cb) acc[rb][cb] = (f32x16)(0.f);

  const char* Abase = (const char*)A_sh + lo * 1024;   // + rb*32768
  const int x7 = lo & 7;
  const unsigned short* Bread = B_sh + w * 2048 + l * 8;

#pragma unroll
  for (int ks = 0; ks < 32; ++ks) {
    // LOAD-BEARING fence: blocks stage16(ks+1) (same-buffer write as the
    // PREVIOUS iteration's bv reads when hoisted) from moving up. See header.
    __builtin_amdgcn_sched_barrier(0);
    if (ks < 31) {
      // stage next chunk into the other buffer (private region, no race)
      stage16(Wsrc + (ks + 1) * 1024 + l * 8,       Bdst + ((ks + 1) & 1) * 1024);
      stage16(Wsrc + (ks + 1) * 1024 + 512 + l * 8, Bdst + ((ks + 1) & 1) * 1024 + 512);
      __builtin_amdgcn_sched_barrier(0);
      asm volatile("s_waitcnt vmcnt(2)" ::: "memory");   // chunk ks landed
    } else {
      asm volatile("s_waitcnt vmcnt(0)" ::: "memory");
    }
    __builtin_amdgcn_sched_barrier(0);

    u16x8 bv[2], av[2];
#pragma unroll
    for (int cb = 0; cb < 2; ++cb)
      bv[cb] = *(const u16x8*)(Bread + (ks & 1) * 1024 + cb * 512);
#pragma unroll
    for (int rb = 0; rb < 2; ++rb)
      av[rb] = *(const u16x8*)(Abase + rb * 32768 + (((2 * ks + hi) ^ x7) << 4));
#pragma unroll
    for (int rb = 0; rb < 2; ++rb)
#pragma unroll
      for (int cb = 0; cb < 2; ++cb)
        acc[rb][cb] = mfma32(av[rb], bv[cb], acc[rb][cb]);
  }

  // ---- epilogue: + b2, row-sums of 2^(x*log2e) via FOLD-reduce ----
  // thread holds: cols {w*64 + cb*32 + lo}, rows {rb*32 + (reg&3)+8*(reg>>2)+4*hi}.
  // Fold: butterfly ^16 (all-keep), then folds 8/4/2/1 keeping half the regs;
  // lane lo ends with the full 32-lane sum for reg = lo&15 (lanes lo, lo+16
  // duplicate the same value -> benign same-value LDS write).
  const float L2E = 1.4426950408889634f;
  const float LN2 = 0.6931471805599453f;

#pragma unroll
  for (int rb = 0; rb < 2; ++rb) {
    float s[16];
#pragma unroll
    for (int reg = 0; reg < 16; ++reg) {
      const float x0 = acc[rb][0][reg] + b2v[0];
      const float x1 = acc[rb][1][reg] + b2v[1];
      acc[rb][0][reg] = x0;
      acc[rb][1][reg] = x1;
      s[reg] = __builtin_amdgcn_exp2f(x0 * L2E) + __builtin_amdgcn_exp2f(x1 * L2E);
    }
#pragma unroll
    for (int reg = 0; reg < 16; ++reg) s[reg] += __shfl_xor(s[reg], 16);
#pragma unroll
    for (int half = 8; half >= 1; half >>= 1) {
#pragma unroll
      for (int j = 0; j < half; ++j) {
        const float a = s[j], c = s[j + half];
        const float sent = (lo & half) ? a : c;     // give away the half I drop
        const float got  = __shfl_xor(sent, half);  // partner's giveaway = my keep-half
        s[j] = ((lo & half) ? c : a) + got;
      }
    }
    const int reg = lo & 15;
    const int row = rb * 32 + (reg & 3) + 8 * (reg >> 2) + 4 * hi;
    red[row][w] = s[0];
  }
  __syncthreads();

  // merge the 16 wave-partials: thread tid<64 handles row tid
  if (tid < 64) {
    float s = red[tid][0];
#pragma unroll
    for (int ww = 1; ww < 16; ++ww) s += red[tid][ww];
    lse_sh[tid] = LN2 * __builtin_amdgcn_logf(s);   // v_log_f32 = log2
  }
  __syncthreads();

  // final: out = acc - lse
  float* outb = out + (size_t)blk * 65536 + w * 64 + lo;
#pragma unroll
  for (int rb = 0; rb < 2; ++rb)
#pragma unroll
    for (int reg = 0; reg < 16; ++reg) {
      const int row = rb * 32 + (reg & 3) + 8 * (reg >> 2) + 4 * hi;
      const float lse = lse_sh[row];
      float* orow = outb + (size_t)row * 1024;
      orow[0]  = acc[rb][0][reg] - lse;
      orow[32] = acc[rb][1][reg] - lse;
    }
}

extern "C" void kernel_launch(void* const* d_in, const int* in_sizes, int n_in,
                              void* d_out, int out_size, void* d_ws, size_t ws_size,
                              hipStream_t stream) {
  (void)in_sizes; (void)n_in; (void)out_size; (void)ws_size;
  const float* enc = (const float*)d_in[0];
  const float* dec = (const float*)d_in[1];
  const float* W1  = (const float*)d_in[2];
  const float* b1  = (const float*)d_in[3];
  const float* W2  = (const float*)d_in[4];
  const float* b2  = (const float*)d_in[5];
  float* out = (float*)d_out;

  char* ws = (char*)d_ws;
  unsigned short* W2t = (unsigned short*)(ws + 0);         // 1 MiB (524288 el, tiled)
  float*          pe  = (float*)(ws + 1048576);            // 2 MiB  [1024][512]
  float*          pd  = (float*)(ws + 3145728);            // 512 KiB [256][512]

  prep_proj_kernel<<<288, 256, 0, stream>>>(enc, dec, W1, W2, b1, W2t, pe, pd);
  joint_kernel<<<1024, 1024, 0, stream>>>(pe, pd, W2t, b2, out);
}

// Round 20
// 139.539 us; speedup vs baseline: 1.1067x; 1.0109x over previous
//
#include <hip/hip_runtime.h>
#include <hip/hip_bf16.h>
#include <stdint.h>

// B=4, M=256, N=64, D=512, C=1024
// out[b,m,n,c] = log_softmax_c( tanh(pe[b,m,:] + pd[b,n,:]) . W2[c,:] + b2[c] )
// pe = enc @ W1[:, :D]^T ; pd = dec @ W1[:, D:]^T + b1
// log_softmax WITHOUT the max pass (logits bounded ~18 -> f32-safe).
// GEMM: v_mfma_f32_32x32x16_bf16; B staged via global_load_lds, QUAD-buffered
// 512-el halves per wave (same 2048-el footprint), depth-3 prefetch,
// counted s_waitcnt vmcnt(3). No barriers in the k-loop.
// CORRECTNESS FENCE (R15/R17 lesson): the half-iter TOP sched_barrier(0) is
// load-bearing — stage(hc+3) writes the buffer last read at iter hc-1; the
// fence stops the scheduler hoisting the stage above those reads. Do not remove.
// W2t layout (both sides): idx = w*32768 + ks*1024 + cb*512 + l*8 + e
//   col = w*64 + cb*32 + (l&31),  k = ks*16 + (l>>5)*8 + e
//   half h = 2*ks + cb  (els [h*512, h*512+512))

typedef __bf16         bf16x8 __attribute__((ext_vector_type(8)));
typedef float          f32x4  __attribute__((ext_vector_type(4)));
typedef float          f32x16 __attribute__((ext_vector_type(16)));
typedef unsigned short u16x8  __attribute__((ext_vector_type(8)));

__device__ __forceinline__ unsigned short f2bf(float f) {
  unsigned int u = __float_as_uint(f);
  u += 0x7fffu + ((u >> 16) & 1u);          // RNE
  return (unsigned short)(u >> 16);
}

__device__ __forceinline__ u16x8 cvt8(const float* p) {
  const float4 a = *(const float4*)p;
  const float4 b = *(const float4*)(p + 4);
  u16x8 r;
  r[0] = f2bf(a.x); r[1] = f2bf(a.y); r[2] = f2bf(a.z); r[3] = f2bf(a.w);
  r[4] = f2bf(b.x); r[5] = f2bf(b.y); r[6] = f2bf(b.z); r[7] = f2bf(b.w);
  return r;
}

__device__ __forceinline__ f32x4 mfma16(u16x8 a, u16x8 b, f32x4 c) {
  return __builtin_amdgcn_mfma_f32_16x16x32_bf16(
      __builtin_bit_cast(bf16x8, a), __builtin_bit_cast(bf16x8, b), c, 0, 0, 0);
}
__device__ __forceinline__ f32x16 mfma32(u16x8 a, u16x8 b, f32x16 c) {
  return __builtin_amdgcn_mfma_f32_32x32x16_bf16(
      __builtin_bit_cast(bf16x8, a), __builtin_bit_cast(bf16x8, b), c, 0, 0, 0);
}

// async global->LDS, 16B/lane: lane i's 16B lands at ldsbase + i*16.
__device__ __forceinline__ void stage16(const void* g, void* l) {
  __builtin_amdgcn_global_load_lds(
      (const __attribute__((address_space(1))) void*)g,
      (__attribute__((address_space(3))) void*)l, 16, 0, 0);
}

// ---------------- prep_proj (fused): proj from f32 inputs + W2 tiling -------
// grid = 288 blocks x 256 threads.
//   blocks   0..127: pe tile (rtile = bid>>3 in 0..15, ctile = bid&7)
//   blocks 128..159: pd tile (+ b1)
//   blocks 160..287: W2 -> W2t bf16 tiling, COALESCED reads
__global__ __launch_bounds__(256) void prep_proj_kernel(
    const float* __restrict__ enc, const float* __restrict__ dec,
    const float* __restrict__ W1,  const float* __restrict__ W2,
    const float* __restrict__ b1,
    unsigned short* __restrict__ W2t, float* __restrict__ pe, float* __restrict__ pd)
{
  const int bid = blockIdx.x;
  if (bid >= 160) {
    // thread -> (col, k8): reads contiguous (2KB per 64-tid group), writes 16B scattered
#pragma unroll
    for (int j = 0; j < 2; ++j) {
      const int idx = (bid - 160) * 512 + j * 256 + threadIdx.x;   // 0..65535
      const int k8  = idx & 63;
      const int col = idx >> 6;
      const u16x8 v = cvt8(W2 + (size_t)col * 512 + k8 * 8);
      const int w  = col >> 6, cb = (col >> 5) & 1;
      const int ks = k8 >> 1;
      const int l  = (col & 31) | ((k8 & 1) << 5);
      *(u16x8*)(W2t + ((size_t)w * 32768 + ks * 1024 + cb * 512 + l * 8)) = v;
    }
    return;
  }

  int pb = bid;
  const float* Af;
  const float* bias;
  float* outp;
  int woff;
  if (pb < 128) { Af = enc; bias = nullptr; outp = pe; woff = 0; }
  else { pb -= 128; Af = dec; bias = b1; outp = pd; woff = 512; }
  const int rtile = pb >> 3;
  const int ctile = pb & 7;
  const int w = threadIdx.x >> 6;
  const int l = threadIdx.x & 63;
  const int q = l >> 4, ln = l & 15;

  f32x4 acc[4] = {};
  const float* Ab = Af + (size_t)(rtile * 64 + ln) * 512 + q * 8;
  const float* Wb = W1 + (size_t)(ctile * 64 + w * 16 + ln) * 1024 + woff + q * 8;

  for (int ks = 0; ks < 16; ++ks) {
    u16x8 bv = cvt8(Wb + ks * 32);
#pragma unroll
    for (int rf = 0; rf < 4; ++rf) {
      u16x8 av = cvt8(Ab + rf * 16 * 512 + ks * 32);
      acc[rf] = mfma16(av, bv, acc[rf]);
    }
  }
  const int col = ctile * 64 + w * 16 + ln;
  const float bv = bias ? bias[col] : 0.0f;
#pragma unroll
  for (int rf = 0; rf < 4; ++rf)
#pragma unroll
    for (int j = 0; j < 4; ++j)
      outp[(size_t)(rtile * 64 + rf * 16 + q * 4 + j) * 512 + col] = acc[rf][j] + bv;
}

// ---------------- joint: fused tanh-GEMM(32x32, LDS-staged B) + log_softmax --
// grid = B*M = 1024 blocks, block = 1024 threads (16 waves).
// Wave w: all 64 rows x cols [w*64, w*64+64) via 2x2 fragments of 32x32.
__global__ __launch_bounds__(1024) void joint_kernel(
    const float* __restrict__ pe, const float* __restrict__ pd,
    const unsigned short* __restrict__ W2t, const float* __restrict__ b2,
    float* __restrict__ out)
{
  __shared__ unsigned short A_sh[64 * 512];    // 64 KiB, XOR-swizzled bf16 tile
  __shared__ unsigned short B_sh[16 * 2048];   // 64 KiB: per-wave 4-buf x 512 els
  __shared__ float red[64][17];                // per-row, per-wave sum2exp (padded)
  __shared__ float lse_sh[64];

  const int blk = blockIdx.x;            // b*256 + m
  const int b   = blk >> 8;
  const int tid = threadIdx.x;
  const int w = tid >> 6, l = tid & 63;
  const int lo = l & 31, hi = l >> 5;

  const unsigned short* Wsrc = W2t + (size_t)w * 32768;   // this wave's panel
  unsigned short* Bdst = B_sh + w * 2048;                 // wave-uniform base

  // stage halves 0,1,2 (bufs 0,1,2) — latency hides under the gen phase
  stage16(Wsrc + l * 8,        Bdst);
  stage16(Wsrc + 512 + l * 8,  Bdst + 512);
  stage16(Wsrc + 1024 + l * 8, Bdst + 1024);

  // b2: load AND pin consumption before the barrier (keep-alive) so no
  // non-stage vmem op can be sunk into the k-loop (vmcnt count depends on it)
  float b2v[2];
#pragma unroll
  for (int cb = 0; cb < 2; ++cb) b2v[cb] = b2[w * 64 + cb * 32 + lo];
  asm volatile("" :: "v"(b2v[0]), "v"(b2v[1]));

  // ---- generate A[n][d] = tanh(pe[m,d] + pd[n,d]) into swizzled LDS ----
  // wave w owns rows w*4..w*4+3; lane l owns d = l*8..l*8+7 (coalesced).
  {
    const float* per = pe + (size_t)blk * 512 + l * 8;
    const float4 pe0 = *(const float4*)(per);
    const float4 pe1 = *(const float4*)(per + 4);
#pragma unroll
    for (int r = 0; r < 4; ++r) {
      const int n = (w << 2) | r;
      const float* pdr = pd + (size_t)((b << 6) | n) * 512 + l * 8;
      const float4 q0 = *(const float4*)(pdr);
      const float4 q1 = *(const float4*)(pdr + 4);
      float x[8] = {pe0.x + q0.x, pe0.y + q0.y, pe0.z + q0.z, pe0.w + q0.w,
                    pe1.x + q1.x, pe1.y + q1.y, pe1.z + q1.z, pe1.w + q1.w};
      u16x8 pk;
#pragma unroll
      for (int e = 0; e < 8; ++e) {
        const float ex = __expf(2.0f * x[e]);                    // tanh = 1 - 2/(e^2x+1)
        const float tv = 1.0f - 2.0f * __builtin_amdgcn_rcpf(ex + 1.0f);
        pk[e] = f2bf(tv);
      }
      *(u16x8*)((char*)A_sh + n * 1024 + ((l ^ (n & 7)) << 4)) = pk;
    }
  }
  __syncthreads();   // A ready; drains gen loads + b2 + stages 0-2: vmcnt = 0 here

  // ---- GEMM: barrier-free half-chunk loop; per-wave quad B buffer ----
  f32x16 acc[2][2];
#pragma unroll
  for (int rb = 0; rb < 2; ++rb)
#pragma unroll
    for (int cb = 0; cb < 2; ++cb) acc[rb][cb] = (f32x16)(0.f);

  const char* Abase = (const char*)A_sh + lo * 1024;   // + rb*32768
  const int x7 = lo & 7;
  const unsigned short* Bread = B_sh + w * 2048 + l * 8;

  u16x8 av[2];
#pragma unroll
  for (int hc = 0; hc < 64; ++hc) {
    // LOAD-BEARING fence: stage(hc+3) writes the buffer last read at hc-1;
    // this stops the scheduler hoisting the stage above those reads.
    __builtin_amdgcn_sched_barrier(0);
    if (hc < 61) {
      stage16(Wsrc + (hc + 3) * 512 + l * 8, Bdst + ((hc + 3) & 3) * 512);
      __builtin_amdgcn_sched_barrier(0);
      asm volatile("s_waitcnt vmcnt(3)" ::: "memory");   // half hc landed
    } else if (hc == 61) {
      asm volatile("s_waitcnt vmcnt(2)" ::: "memory");
    } else if (hc == 62) {
      asm volatile("s_waitcnt vmcnt(1)" ::: "memory");
    } else {
      asm volatile("s_waitcnt vmcnt(0)" ::: "memory");
    }
    __builtin_amdgcn_sched_barrier(0);

    const int cb = hc & 1;
    u16x8 bv = *(const u16x8*)(Bread + (hc & 3) * 512);
    if (cb == 0) {
      const int ks = hc >> 1;
#pragma unroll
      for (int rb = 0; rb < 2; ++rb)
        av[rb] = *(const u16x8*)(Abase + rb * 32768 + (((2 * ks + hi) ^ x7) << 4));
    }
#pragma unroll
    for (int rb = 0; rb < 2; ++rb)
      acc[rb][cb] = mfma32(av[rb], bv, acc[rb][cb]);
  }

  // ---- epilogue: + b2, row-sums of 2^(x*log2e) via FOLD-reduce ----
  // thread holds: cols {w*64 + cb*32 + lo}, rows {rb*32 + (reg&3)+8*(reg>>2)+4*hi}.
  const float L2E = 1.4426950408889634f;
  const float LN2 = 0.6931471805599453f;

#pragma unroll
  for (int rb = 0; rb < 2; ++rb) {
    float s[16];
#pragma unroll
    for (int reg = 0; reg < 16; ++reg) {
      const float x0 = acc[rb][0][reg] + b2v[0];
      const float x1 = acc[rb][1][reg] + b2v[1];
      acc[rb][0][reg] = x0;
      acc[rb][1][reg] = x1;
      s[reg] = __builtin_amdgcn_exp2f(x0 * L2E) + __builtin_amdgcn_exp2f(x1 * L2E);
    }
#pragma unroll
    for (int reg = 0; reg < 16; ++reg) s[reg] += __shfl_xor(s[reg], 16);
#pragma unroll
    for (int half = 8; half >= 1; half >>= 1) {
#pragma unroll
      for (int j = 0; j < half; ++j) {
        const float a = s[j], c = s[j + half];
        const float sent = (lo & half) ? a : c;     // give away the half I drop
        const float got  = __shfl_xor(sent, half);  // partner's giveaway = my keep-half
        s[j] = ((lo & half) ? c : a) + got;
      }
    }
    const int reg = lo & 15;
    const int row = rb * 32 + (reg & 3) + 8 * (reg >> 2) + 4 * hi;
    red[row][w] = s[0];
  }
  __syncthreads();

  // merge the 16 wave-partials: thread tid<64 handles row tid
  if (tid < 64) {
    float s = red[tid][0];
#pragma unroll
    for (int ww = 1; ww < 16; ++ww) s += red[tid][ww];
    lse_sh[tid] = LN2 * __builtin_amdgcn_logf(s);   // v_log_f32 = log2
  }
  __syncthreads();

  // final: out = acc - lse
  float* outb = out + (size_t)blk * 65536 + w * 64 + lo;
#pragma unroll
  for (int rb = 0; rb < 2; ++rb)
#pragma unroll
    for (int reg = 0; reg < 16; ++reg) {
      const int row = rb * 32 + (reg & 3) + 8 * (reg >> 2) + 4 * hi;
      const float lse = lse_sh[row];
      float* orow = outb + (size_t)row * 1024;
      orow[0]  = acc[rb][0][reg] - lse;
      orow[32] = acc[rb][1][reg] - lse;
    }
}

extern "C" void kernel_launch(void* const* d_in, const int* in_sizes, int n_in,
                              void* d_out, int out_size, void* d_ws, size_t ws_size,
                              hipStream_t stream) {
  (void)in_sizes; (void)n_in; (void)out_size; (void)ws_size;
  const float* enc = (const float*)d_in[0];
  const float* dec = (const float*)d_in[1];
  const float* W1  = (const float*)d_in[2];
  const float* b1  = (const float*)d_in[3];
  const float* W2  = (const float*)d_in[4];
  const float* b2  = (const float*)d_in[5];
  float* out = (float*)d_out;

  char* ws = (char*)d_ws;
  unsigned short* W2t = (unsigned short*)(ws + 0);         // 1 MiB (524288 el, tiled)
  float*          pe  = (float*)(ws + 1048576);            // 2 MiB  [1024][512]
  float*          pd  = (float*)(ws + 3145728);            // 512 KiB [256][512]

  prep_proj_kernel<<<288, 256, 0, stream>>>(enc, dec, W1, W2, b1, W2t, pe, pd);
  joint_kernel<<<1024, 1024, 0, stream>>>(pe, pd, W2t, b2, out);
}